// Round 2
// baseline (726.214 us; speedup 1.0000x reference)
//
#include <hip/hip_runtime.h>
#include <stdint.h>

// ---------------------------------------------------------------------------
// SelfAttnV3: qkv = x@Wqkv+b; S = Q@K^T/sqrt(D); p = softmax(S);
//             w2 = softmax(mask ? p : -1e20); out = (w2@V)@Wout + b_out
// Double-softmax identity: exp(-1e20-m)==0, p<=1 => w2 = mask*exp(p)/sum(mask*exp(p))
// All GEMMs bf16 MFMA (16x16x32), NT form (B given as [N,K] row-major).
// R2: LDS k-chunk XOR swizzle (kills 8-way bank conflicts; staging-side permute
//     since global_load_lds can't scatter); softmax in-place (w2 over S).
// ---------------------------------------------------------------------------

#define NN 2048
#define DD 1024

typedef __attribute__((ext_vector_type(8))) __bf16 bf16x8;
typedef __attribute__((ext_vector_type(4))) float f32x4;
typedef __attribute__((ext_vector_type(8))) unsigned short us8;
typedef __attribute__((ext_vector_type(4))) unsigned short us4;

__device__ __forceinline__ unsigned short f2bf(float f) {
  unsigned u = __builtin_bit_cast(unsigned, f);
  return (unsigned short)((u + 0x7FFFu + ((u >> 16) & 1u)) >> 16);  // RNE
}
__device__ __forceinline__ float bf2f(unsigned short h) {
  unsigned u = ((unsigned)h) << 16;
  return __builtin_bit_cast(float, u);
}

// async global->LDS, 16B per lane. LDS dest must be wave-uniform base + lane*16.
__device__ __forceinline__ void async16(const void* g, void* l) {
  __builtin_amdgcn_global_load_lds(
      (__attribute__((address_space(1))) void*)(uintptr_t)g,
      (__attribute__((address_space(3))) void*)(uintptr_t)l,
      16, 0, 0);
}

// ---------------------------------------------------------------------------
// fp32 -> bf16 elementwise convert (vectorized)
// ---------------------------------------------------------------------------
__global__ __launch_bounds__(256) void cvt_bf16(const float* __restrict__ src,
                                                unsigned short* __restrict__ dst,
                                                long n) {
  long i = ((long)blockIdx.x * 256 + threadIdx.x) * 4;
  long stride = (long)gridDim.x * 256 * 4;
  for (; i < n; i += stride) {
    float4 v = *reinterpret_cast<const float4*>(src + i);
    us4 o;
    o[0] = f2bf(v.x); o[1] = f2bf(v.y); o[2] = f2bf(v.z); o[3] = f2bf(v.w);
    *reinterpret_cast<us4*>(dst + i) = o;
  }
}

// ---------------------------------------------------------------------------
// fp32 [rows,cols] -> bf16 [cols,rows] transpose (for weights)
// ---------------------------------------------------------------------------
__global__ __launch_bounds__(256) void transpose_cvt(const float* __restrict__ src,
                                                     unsigned short* __restrict__ dst,
                                                     int rows, int cols) {
  __shared__ float t[32][33];
  const int tx = threadIdx.x & 31, ty = threadIdx.x >> 5;
  const int c0 = blockIdx.x * 32, r0 = blockIdx.y * 32;
#pragma unroll
  for (int i = 0; i < 32; i += 8)
    t[ty + i][tx] = src[(long)(r0 + ty + i) * cols + (c0 + tx)];
  __syncthreads();
#pragma unroll
  for (int i = 0; i < 32; i += 8)
    dst[(long)(c0 + ty + i) * rows + (r0 + tx)] = f2bf(t[tx][ty + i]);
}

// ---------------------------------------------------------------------------
// V slice of qkv [per-batch 2048 x 1024, row stride 3072] -> vt [1024 x 2048]
// ---------------------------------------------------------------------------
__global__ __launch_bounds__(256) void transpose_v(const unsigned short* __restrict__ qkv,
                                                   unsigned short* __restrict__ vt) {
  __shared__ unsigned short t[32][33];
  const int tx = threadIdx.x & 31, ty = threadIdx.x >> 5;
  const int c0 = blockIdx.x * 32, r0 = blockIdx.y * 32;  // c: d (1024), r: n (2048)
  const long z = blockIdx.z;
  const unsigned short* src = qkv + z * (long)NN * 3072 + 2 * DD;
  unsigned short* dst = vt + z * (long)DD * NN;
#pragma unroll
  for (int i = 0; i < 32; i += 8)
    t[ty + i][tx] = src[(long)(r0 + ty + i) * 3072 + (c0 + tx)];
  __syncthreads();
#pragma unroll
  for (int i = 0; i < 32; i += 8)
    dst[(long)(c0 + ty + i) * NN + (r0 + tx)] = t[tx][ty + i];
}

// ---------------------------------------------------------------------------
// NT bf16 GEMM, m97 structure: C[M,N] = A[M,K] @ B[N,K]^T (*scale) (+bias)
// 128x128 tile, BK=32, 256 threads = 4 waves (2x2 of 64x64), single-buffered LDS,
// global_load_lds width-16 staging, mfma_f32_16x16x32_bf16.
//
// LDS swizzle: a row's 4 16B k-chunks are stored permuted: physical chunk p of
// row r holds logical chunk p ^ (r&3). Staging thread t (row=t>>2) therefore
// FETCHES logical chunk (t&3)^((t>>2)&3) into its fixed LDS slot (same 64B per
// 4-thread group -> global coalescing unchanged). Fragment reads use physical
// chunk q^(fr&3) (loop-invariant per lane). Bank sets become 2-way (free)
// instead of 8-way.
// ---------------------------------------------------------------------------
template <bool BIAS, bool OUTF32>
__global__ __launch_bounds__(256) void gemm_bt(
    const unsigned short* __restrict__ A, long lda, long sA,
    const unsigned short* __restrict__ B, long ldb, long sB,
    void* __restrict__ Cv, long ldc, long sC,
    const float* __restrict__ bias, int K, float scale) {
  __shared__ __attribute__((aligned(16))) unsigned short As[128 * 32];
  __shared__ __attribute__((aligned(16))) unsigned short Bs[128 * 32];
  const int tid = threadIdx.x;
  const long bm = blockIdx.y, bn = blockIdx.x, bz = blockIdx.z;
  A += bz * sA + bm * 128 * lda;
  B += bz * sB + bn * 128 * ldb;

  // staging: thread t loads (row=t>>2, physical chunk t&3) and (row+64, same)
  const int r0 = tid >> 2;
  const int kx8 = (((tid & 3) ^ (r0 & 3)) * 8);  // swizzled logical chunk offset
  const unsigned short* Ar0 = A + (long)r0 * lda + kx8;
  const unsigned short* Ar1 = A + (long)(r0 + 64) * lda + kx8;
  const unsigned short* Br0 = B + (long)r0 * ldb + kx8;
  const unsigned short* Br1 = B + (long)(r0 + 64) * ldb + kx8;
  unsigned short* lA0 = &As[tid * 8];
  unsigned short* lA1 = &As[(tid + 256) * 8];
  unsigned short* lB0 = &Bs[tid * 8];
  unsigned short* lB1 = &Bs[(tid + 256) * 8];

  f32x4 acc[4][4] = {};
  const int lane = tid & 63;
  const int wm = (tid >> 7) * 64;         // wave row (2x2 wave grid)
  const int wn = ((tid >> 6) & 1) * 64;   // wave col
  const int fr = lane & 15;               // frag row (A) / col (B)
  // physical chunk for logical k-quad (lane>>4), undoing the staging swizzle:
  const int kqs = (((lane >> 4) ^ (fr & 3)) * 8);

  for (int kt = 0; kt < K; kt += 32) {
    async16(Ar0 + kt, lA0);
    async16(Ar1 + kt, lA1);
    async16(Br0 + kt, lB0);
    async16(Br1 + kt, lB1);
    __syncthreads();  // compiler emits vmcnt(0) drain before barrier
    bf16x8 a[4], b[4];
#pragma unroll
    for (int i = 0; i < 4; i++)
      a[i] = *reinterpret_cast<const bf16x8*>(&As[(wm + i * 16 + fr) * 32 + kqs]);
#pragma unroll
    for (int i = 0; i < 4; i++)
      b[i] = *reinterpret_cast<const bf16x8*>(&Bs[(wn + i * 16 + fr) * 32 + kqs]);
#pragma unroll
    for (int mi = 0; mi < 4; mi++)
#pragma unroll
      for (int ni = 0; ni < 4; ni++)
        acc[mi][ni] = __builtin_amdgcn_mfma_f32_16x16x32_bf16(a[mi], b[ni], acc[mi][ni], 0, 0, 0);
    __syncthreads();
  }

  // epilogue: C/D layout col=lane&15, row=(lane>>4)*4+reg (m89-verified)
  const int cr = (lane >> 4) * 4;
  float* Cf = (float*)Cv;
  unsigned short* Ch = (unsigned short*)Cv;
  const long crow0 = bm * 128 + wm;
  const long ccol0 = bn * 128 + wn;
#pragma unroll
  for (int ni = 0; ni < 4; ni++) {
    const long gc = ccol0 + ni * 16 + fr;
    const float bv = BIAS ? bias[gc] : 0.0f;
#pragma unroll
    for (int mi = 0; mi < 4; mi++) {
      const long gr = crow0 + mi * 16 + cr;
#pragma unroll
      for (int r = 0; r < 4; r++) {
        float v = acc[mi][ni][r] * scale + bv;
        long idx = bz * sC + (gr + r) * ldc + gc;
        if (OUTF32) Cf[idx] = v;
        else        Ch[idx] = f2bf(v);
      }
    }
  }
}

// ---------------------------------------------------------------------------
// Fused double softmax per row: p = softmax(s); w2 = mask*exp(p)/sum(mask*exp(p))
// One block (256 thr) per row; 8 elements/thread in registers. In-place (W2==S ok).
// ---------------------------------------------------------------------------
__global__ __launch_bounds__(256) void softmax2(const unsigned short* __restrict__ S,
                                                const int* __restrict__ mask,
                                                unsigned short* __restrict__ W2,
                                                int b0) {
  const int q = blockIdx.x;
  const int zb = blockIdx.y;
  const int tid = threadIdx.x;
  const int lane = tid & 63, wave = tid >> 6;
  const long rl = ((long)zb * NN + q) * NN;
  const unsigned short* srow = S + rl;
  unsigned short* wrow = W2 + rl;
  const int* mrow = mask + ((long)(b0 + zb) * NN + q) * NN;

  us8 sv = *reinterpret_cast<const us8*>(srow + tid * 8);
  float s[8];
#pragma unroll
  for (int j = 0; j < 8; j++) s[j] = bf2f(sv[j]);

  __shared__ float redm[4], redl[4], redt[4];

  // --- softmax 1: max ---
  float m = s[0];
#pragma unroll
  for (int j = 1; j < 8; j++) m = fmaxf(m, s[j]);
  for (int o = 32; o; o >>= 1) m = fmaxf(m, __shfl_xor(m, o));
  if (lane == 0) redm[wave] = m;
  __syncthreads();
  m = fmaxf(fmaxf(redm[0], redm[1]), fmaxf(redm[2], redm[3]));

  // --- softmax 1: sum ---
  float p[8];
  float ls = 0.0f;
#pragma unroll
  for (int j = 0; j < 8; j++) { p[j] = __expf(s[j] - m); ls += p[j]; }
  for (int o = 32; o; o >>= 1) ls += __shfl_xor(ls, o);
  if (lane == 0) redl[wave] = ls;
  __syncthreads();
  ls = redl[0] + redl[1] + redl[2] + redl[3];
  const float invL = 1.0f / ls;

  // --- mask + softmax 2 (p in [0,1]: no max-sub needed; masked -> exactly 0) ---
  int4 m0 = *reinterpret_cast<const int4*>(mrow + tid * 8);
  int4 m1 = *reinterpret_cast<const int4*>(mrow + tid * 8 + 4);
  const int mk[8] = {m0.x, m0.y, m0.z, m0.w, m1.x, m1.y, m1.z, m1.w};
  float t[8];
  float ts = 0.0f;
#pragma unroll
  for (int j = 0; j < 8; j++) {
    float e = (mk[j] != 0) ? __expf(p[j] * invL) : 0.0f;
    t[j] = e;
    ts += e;
  }
  for (int o = 32; o; o >>= 1) ts += __shfl_xor(ts, o);
  if (lane == 0) redt[wave] = ts;
  __syncthreads();
  ts = redt[0] + redt[1] + redt[2] + redt[3];

  us8 ov;
  if (ts > 0.0f) {
    const float invT = 1.0f / ts;
#pragma unroll
    for (int j = 0; j < 8; j++) ov[j] = f2bf(t[j] * invT);
  } else {  // all-masked row: reference softmax of uniform -1e20 -> 1/N
#pragma unroll
    for (int j = 0; j < 8; j++) ov[j] = f2bf(1.0f / (float)NN);
  }
  *reinterpret_cast<us8*>(wrow + tid * 8) = ov;
}

// ---------------------------------------------------------------------------
extern "C" void kernel_launch(void* const* d_in, const int* in_sizes, int n_in,
                              void* d_out, int out_size, void* d_ws, size_t ws_size,
                              hipStream_t stream) {
  const float* x = (const float*)d_in[0];
  const int* mask = (const int*)d_in[1];
  const float* Wqkv = (const float*)d_in[2];
  const float* bqkv = (const float*)d_in[3];
  const float* Wout = (const float*)d_in[4];
  const float* bout = (const float*)d_in[5];
  float* out = (float*)d_out;

  char* p = (char*)d_ws;
  unsigned short* xb = (unsigned short*)p;    p += (long)16384 * 1024 * 2;   // 33.5MB
  unsigned short* wqkvt = (unsigned short*)p; p += (long)3072 * 1024 * 2;    // 6.3MB
  unsigned short* woutt = (unsigned short*)p; p += (long)1024 * 1024 * 2;    // 2.1MB
  unsigned short* qkv = (unsigned short*)p;   p += (long)16384 * 3072 * 2;   // 100.7MB
  unsigned short* vt = (unsigned short*)p;    p += (long)8 * 1024 * 2048 * 2;// 33.5MB
  unsigned short* attn = (unsigned short*)p;  p += (long)16384 * 1024 * 2;   // 33.5MB
  const long fixed = (long)(p - (char*)d_ws);

  // batch chunk for S (bf16 [chunk,2048,2048]); softmax runs in-place (w2 == S)
  int chunk = 8;
  while (chunk > 1 && fixed + (long)chunk * NN * NN * 2 > (long)ws_size) chunk >>= 1;
  unsigned short* S = (unsigned short*)p;

  // 1) convert x to bf16; transpose-convert weights
  cvt_bf16<<<4096, 256, 0, stream>>>(x, xb, (long)16384 * 1024);
  transpose_cvt<<<dim3(3072 / 32, 1024 / 32), 256, 0, stream>>>(Wqkv, wqkvt, 1024, 3072);
  transpose_cvt<<<dim3(1024 / 32, 1024 / 32), 256, 0, stream>>>(Wout, woutt, 1024, 1024);

  // 2) QKV projection: [16384,1024] @ [3072,1024]^T + b -> qkv bf16 [16384,3072]
  gemm_bt<true, false><<<dim3(24, 128, 1), 256, 0, stream>>>(
      xb, 1024, 0, wqkvt, 1024, 0, qkv, 3072, 0, bqkv, 1024, 1.0f);

  // 3) V^T per batch for the PV NT-GEMM
  transpose_v<<<dim3(32, 64, 8), 256, 0, stream>>>(qkv, vt);

  // 4) attention per batch-chunk
  for (int b0 = 0; b0 < 8; b0 += chunk) {
    // S = Q @ K^T / 32  (bf16 out)
    gemm_bt<false, false><<<dim3(16, 16, chunk), 256, 0, stream>>>(
        qkv + (long)b0 * NN * 3072, 3072, (long)NN * 3072,
        qkv + (long)b0 * NN * 3072 + 1024, 3072, (long)NN * 3072,
        S, NN, (long)NN * NN, nullptr, 1024, 0.03125f);
    // fused softmax -> mask -> softmax (in-place)
    softmax2<<<dim3(NN, chunk), 256, 0, stream>>>(S, mask, S, b0);
    // attn = w2 @ V  ( = S @ vt^T )
    gemm_bt<false, false><<<dim3(8, 16, chunk), 256, 0, stream>>>(
        S, NN, (long)NN * NN,
        vt + (long)b0 * DD * NN, NN, (long)DD * NN,
        attn + (long)b0 * NN * DD, DD, (long)NN * DD, nullptr, 2048, 1.0f);
  }

  // 5) output projection: [16384,1024] @ [1024,1024]^T + b -> fp32 out
  gemm_bt<true, true><<<dim3(8, 128, 1), 256, 0, stream>>>(
      attn, 1024, 0, woutt, 1024, 0, out, 1024, 0, bout, 1024, 1.0f);
}

// Round 3
// 662.237 us; speedup vs baseline: 1.0966x; 1.0966x over previous
//
#include <hip/hip_runtime.h>
#include <stdint.h>

// ---------------------------------------------------------------------------
// SelfAttnV3: qkv = x@Wqkv+b; S = Q@K^T/sqrt(D); p = softmax(S);
//             w2 = softmax(mask ? p : -1e20); out = (w2@V)@Wout + b_out
// Double-softmax identity: exp(-1e20-m)==0, p<=1 => w2 = mask*exp(p)/sum(mask*exp(p))
// All GEMMs bf16 MFMA (16x16x32), NT form.
// R3: (a) V^T produced by its own NT-GEMM (A=Wv^T, B=x, row-bias) -- transpose_v
//     kernel eliminated (-134MB traffic, -1 launch). QK GEMM now N=2048.
//     (b) BK=64 K-loop (32KB LDS): halves barrier count -> attacks the
//     vmcnt(0)+s_barrier drain that limits the m97 structure.
//     R2 lesson: SQ_LDS_BANK_CONFLICT is dominated by global_load_lds write
//     serialization (inherent), not ds_read conflicts.
// ---------------------------------------------------------------------------

#define NN 2048
#define DD 1024

typedef __attribute__((ext_vector_type(8))) __bf16 bf16x8;
typedef __attribute__((ext_vector_type(4))) float f32x4;
typedef __attribute__((ext_vector_type(8))) unsigned short us8;
typedef __attribute__((ext_vector_type(4))) unsigned short us4;

__device__ __forceinline__ unsigned short f2bf(float f) {
  unsigned u = __builtin_bit_cast(unsigned, f);
  return (unsigned short)((u + 0x7FFFu + ((u >> 16) & 1u)) >> 16);  // RNE
}
__device__ __forceinline__ float bf2f(unsigned short h) {
  unsigned u = ((unsigned)h) << 16;
  return __builtin_bit_cast(float, u);
}

// async global->LDS, 16B per lane. LDS dest: wave-uniform base + lane*16.
__device__ __forceinline__ void async16(const void* g, void* l) {
  __builtin_amdgcn_global_load_lds(
      (__attribute__((address_space(1))) void*)(uintptr_t)g,
      (__attribute__((address_space(3))) void*)(uintptr_t)l,
      16, 0, 0);
}

// ---------------------------------------------------------------------------
// fp32 -> bf16 elementwise convert (vectorized)
// ---------------------------------------------------------------------------
__global__ __launch_bounds__(256) void cvt_bf16(const float* __restrict__ src,
                                                unsigned short* __restrict__ dst,
                                                long n) {
  long i = ((long)blockIdx.x * 256 + threadIdx.x) * 4;
  long stride = (long)gridDim.x * 256 * 4;
  for (; i < n; i += stride) {
    float4 v = *reinterpret_cast<const float4*>(src + i);
    us4 o;
    o[0] = f2bf(v.x); o[1] = f2bf(v.y); o[2] = f2bf(v.z); o[3] = f2bf(v.w);
    *reinterpret_cast<us4*>(dst + i) = o;
  }
}

// ---------------------------------------------------------------------------
// fp32 [rows,cols] -> bf16 [cols,rows] transpose (for weights)
// ---------------------------------------------------------------------------
__global__ __launch_bounds__(256) void transpose_cvt(const float* __restrict__ src,
                                                     unsigned short* __restrict__ dst,
                                                     int rows, int cols) {
  __shared__ float t[32][33];
  const int tx = threadIdx.x & 31, ty = threadIdx.x >> 5;
  const int c0 = blockIdx.x * 32, r0 = blockIdx.y * 32;
#pragma unroll
  for (int i = 0; i < 32; i += 8)
    t[ty + i][tx] = src[(long)(r0 + ty + i) * cols + (c0 + tx)];
  __syncthreads();
#pragma unroll
  for (int i = 0; i < 32; i += 8)
    dst[(long)(c0 + ty + i) * rows + (r0 + tx)] = f2bf(t[tx][ty + i]);
}

// ---------------------------------------------------------------------------
// NT bf16 GEMM: C[M,N] = A[M,K] @ B[N,K]^T (*scale) (+bias)
// 128x128 tile, BK=64, 256 threads = 4 waves (2x2 of 64x64), single-buffered
// 32KB LDS, global_load_lds width-16 staging, mfma_f32_16x16x32_bf16.
// LDS row = 64 elems (128B). Chunk swizzle: physical 16B-chunk p of row r holds
// logical chunk p^(r&7); staging thread fetches accordingly (coalescing intact:
// each 8-thread row-group still covers the same 128B). Reader undoes it with a
// loop-invariant per-lane offset.
// BMODE: 0=none, 1=col bias (bias[gc]), 2=row bias (bias[gr]).
// ---------------------------------------------------------------------------
template <int BMODE, bool OUTF32>
__global__ __launch_bounds__(256) void gemm_bt(
    const unsigned short* __restrict__ A, long lda, long sA,
    const unsigned short* __restrict__ B, long ldb, long sB,
    void* __restrict__ Cv, long ldc, long sC,
    const float* __restrict__ bias, int K, float scale) {
  __shared__ __attribute__((aligned(16))) unsigned short As[128 * 64];
  __shared__ __attribute__((aligned(16))) unsigned short Bs[128 * 64];
  const int tid = threadIdx.x;
  const long bm = blockIdx.y, bn = blockIdx.x, bz = blockIdx.z;
  A += bz * sA + bm * 128 * lda;
  B += bz * sB + bn * 128 * ldb;

  // staging: slot s in [0,1024): row=s>>3, phys chunk=s&7. Thread t owns slots
  // t, t+256, t+512, t+768 (rows r0+32j, same phys chunk). Logical chunk
  // fetched = (t&7)^(r0&7), invariant across j (32 == 0 mod 8).
  const int r0 = tid >> 3;
  const int kx = ((tid & 7) ^ (r0 & 7)) * 8;  // element offset in row
  const unsigned short* Ag0 = A + (long)r0 * lda + kx;
  const unsigned short* Ag1 = A + (long)(r0 + 32) * lda + kx;
  const unsigned short* Ag2 = A + (long)(r0 + 64) * lda + kx;
  const unsigned short* Ag3 = A + (long)(r0 + 96) * lda + kx;
  const unsigned short* Bg0 = B + (long)r0 * ldb + kx;
  const unsigned short* Bg1 = B + (long)(r0 + 32) * ldb + kx;
  const unsigned short* Bg2 = B + (long)(r0 + 64) * ldb + kx;
  const unsigned short* Bg3 = B + (long)(r0 + 96) * ldb + kx;
  unsigned short* lA0 = &As[tid * 8];
  unsigned short* lA1 = &As[(tid + 256) * 8];
  unsigned short* lA2 = &As[(tid + 512) * 8];
  unsigned short* lA3 = &As[(tid + 768) * 8];
  unsigned short* lB0 = &Bs[tid * 8];
  unsigned short* lB1 = &Bs[(tid + 256) * 8];
  unsigned short* lB2 = &Bs[(tid + 512) * 8];
  unsigned short* lB3 = &Bs[(tid + 768) * 8];

  f32x4 acc[4][4] = {};
  const int lane = tid & 63;
  const int wm = (tid >> 7) * 64;         // wave row (2x2 wave grid)
  const int wn = ((tid >> 6) & 1) * 64;   // wave col
  const int fr = lane & 15;               // frag row (A) / col (B)
  const int quad = lane >> 4;
  // element offsets of logical k-chunks (kk*4+quad), un-swizzled per lane:
  const int koff0 = ((quad) ^ (fr & 7)) * 8;        // kk=0
  const int koff1 = ((4 + quad) ^ (fr & 7)) * 8;    // kk=1

  for (int kt = 0; kt < K; kt += 64) {
    async16(Ag0 + kt, lA0);
    async16(Ag1 + kt, lA1);
    async16(Ag2 + kt, lA2);
    async16(Ag3 + kt, lA3);
    async16(Bg0 + kt, lB0);
    async16(Bg1 + kt, lB1);
    async16(Bg2 + kt, lB2);
    async16(Bg3 + kt, lB3);
    __syncthreads();  // compiler emits vmcnt(0) drain before barrier
#pragma unroll
    for (int kk = 0; kk < 2; kk++) {
      const int ko = kk ? koff1 : koff0;
      bf16x8 a[4], b[4];
#pragma unroll
      for (int i = 0; i < 4; i++)
        a[i] = *reinterpret_cast<const bf16x8*>(&As[(wm + i * 16 + fr) * 64 + ko]);
#pragma unroll
      for (int i = 0; i < 4; i++)
        b[i] = *reinterpret_cast<const bf16x8*>(&Bs[(wn + i * 16 + fr) * 64 + ko]);
#pragma unroll
      for (int mi = 0; mi < 4; mi++)
#pragma unroll
        for (int ni = 0; ni < 4; ni++)
          acc[mi][ni] = __builtin_amdgcn_mfma_f32_16x16x32_bf16(a[mi], b[ni], acc[mi][ni], 0, 0, 0);
    }
    __syncthreads();
  }

  // epilogue: C/D layout col=lane&15, row=(lane>>4)*4+reg (m89-verified)
  const int cr = quad * 4;
  float* Cf = (float*)Cv;
  unsigned short* Ch = (unsigned short*)Cv;
  const long crow0 = bm * 128 + wm;
  const long ccol0 = bn * 128 + wn;
#pragma unroll
  for (int ni = 0; ni < 4; ni++) {
    const long gc = ccol0 + ni * 16 + fr;
    const float bc = (BMODE == 1) ? bias[gc] : 0.0f;
#pragma unroll
    for (int mi = 0; mi < 4; mi++) {
      const long gr = crow0 + mi * 16 + cr;
#pragma unroll
      for (int r = 0; r < 4; r++) {
        const float bv = (BMODE == 2) ? bias[gr + r] : bc;
        float v = acc[mi][ni][r] * scale + bv;
        long idx = bz * sC + (gr + r) * ldc + gc;
        if (OUTF32) Cf[idx] = v;
        else        Ch[idx] = f2bf(v);
      }
    }
  }
}

// ---------------------------------------------------------------------------
// Fused double softmax per row: p = softmax(s); w2 = mask*exp(p)/sum(mask*exp(p))
// One block (256 thr) per row; 8 elements/thread in registers. In-place OK.
// ---------------------------------------------------------------------------
__global__ __launch_bounds__(256) void softmax2(const unsigned short* __restrict__ S,
                                                const int* __restrict__ mask,
                                                unsigned short* __restrict__ W2,
                                                int b0) {
  const int q = blockIdx.x;
  const int zb = blockIdx.y;
  const int tid = threadIdx.x;
  const int lane = tid & 63, wave = tid >> 6;
  const long rl = ((long)zb * NN + q) * NN;
  const unsigned short* srow = S + rl;
  unsigned short* wrow = W2 + rl;
  const int* mrow = mask + ((long)(b0 + zb) * NN + q) * NN;

  us8 sv = *reinterpret_cast<const us8*>(srow + tid * 8);
  float s[8];
#pragma unroll
  for (int j = 0; j < 8; j++) s[j] = bf2f(sv[j]);

  __shared__ float redm[4], redl[4], redt[4];

  // --- softmax 1: max ---
  float m = s[0];
#pragma unroll
  for (int j = 1; j < 8; j++) m = fmaxf(m, s[j]);
  for (int o = 32; o; o >>= 1) m = fmaxf(m, __shfl_xor(m, o));
  if (lane == 0) redm[wave] = m;
  __syncthreads();
  m = fmaxf(fmaxf(redm[0], redm[1]), fmaxf(redm[2], redm[3]));

  // --- softmax 1: sum ---
  float p[8];
  float ls = 0.0f;
#pragma unroll
  for (int j = 0; j < 8; j++) { p[j] = __expf(s[j] - m); ls += p[j]; }
  for (int o = 32; o; o >>= 1) ls += __shfl_xor(ls, o);
  if (lane == 0) redl[wave] = ls;
  __syncthreads();
  ls = redl[0] + redl[1] + redl[2] + redl[3];
  const float invL = 1.0f / ls;

  // --- mask + softmax 2 (p in [0,1]: no max-sub needed; masked -> exactly 0) ---
  int4 m0 = *reinterpret_cast<const int4*>(mrow + tid * 8);
  int4 m1 = *reinterpret_cast<const int4*>(mrow + tid * 8 + 4);
  const int mk[8] = {m0.x, m0.y, m0.z, m0.w, m1.x, m1.y, m1.z, m1.w};
  float t[8];
  float ts = 0.0f;
#pragma unroll
  for (int j = 0; j < 8; j++) {
    float e = (mk[j] != 0) ? __expf(p[j] * invL) : 0.0f;
    t[j] = e;
    ts += e;
  }
  for (int o = 32; o; o >>= 1) ts += __shfl_xor(ts, o);
  if (lane == 0) redt[wave] = ts;
  __syncthreads();
  ts = redt[0] + redt[1] + redt[2] + redt[3];

  us8 ov;
  if (ts > 0.0f) {
    const float invT = 1.0f / ts;
#pragma unroll
    for (int j = 0; j < 8; j++) ov[j] = f2bf(t[j] * invT);
  } else {  // all-masked row: reference softmax of uniform -1e20 -> 1/N
#pragma unroll
    for (int j = 0; j < 8; j++) ov[j] = f2bf(1.0f / (float)NN);
  }
  *reinterpret_cast<us8*>(wrow + tid * 8) = ov;
}

// ---------------------------------------------------------------------------
extern "C" void kernel_launch(void* const* d_in, const int* in_sizes, int n_in,
                              void* d_out, int out_size, void* d_ws, size_t ws_size,
                              hipStream_t stream) {
  const float* x = (const float*)d_in[0];
  const int* mask = (const int*)d_in[1];
  const float* Wqkv = (const float*)d_in[2];
  const float* bqkv = (const float*)d_in[3];
  const float* Wout = (const float*)d_in[4];
  const float* bout = (const float*)d_in[5];
  float* out = (float*)d_out;

  char* p = (char*)d_ws;
  unsigned short* xb = (unsigned short*)p;    p += (long)16384 * 1024 * 2;   // 33.5MB
  unsigned short* wqkvt = (unsigned short*)p; p += (long)3072 * 1024 * 2;    // 6.3MB
  unsigned short* woutt = (unsigned short*)p; p += (long)1024 * 1024 * 2;    // 2.1MB
  unsigned short* qk = (unsigned short*)p;    p += (long)16384 * 2048 * 2;   // 67.1MB (Q|K interleaved per row)
  unsigned short* vt = (unsigned short*)p;    p += (long)8 * 1024 * 2048 * 2;// 33.5MB
  unsigned short* attn = (unsigned short*)p;  p += (long)16384 * 1024 * 2;   // 33.5MB
  const long fixed = (long)(p - (char*)d_ws);

  // batch chunk for S (bf16 [chunk,2048,2048]); softmax runs in-place (w2 == S)
  int chunk = 8;
  while (chunk > 1 && fixed + (long)chunk * NN * NN * 2 > (long)ws_size) chunk >>= 1;
  unsigned short* S = (unsigned short*)p;

  // 1) convert x to bf16; transpose-convert weights
  cvt_bf16<<<4096, 256, 0, stream>>>(x, xb, (long)16384 * 1024);
  transpose_cvt<<<dim3(3072 / 32, 1024 / 32), 256, 0, stream>>>(Wqkv, wqkvt, 1024, 3072);
  transpose_cvt<<<dim3(1024 / 32, 1024 / 32), 256, 0, stream>>>(Wout, woutt, 1024, 1024);

  // 2a) QK projection: [16384,1024] @ [2048,1024]^T + b -> qk bf16 [16384,2048]
  gemm_bt<1, false><<<dim3(16, 128, 1), 256, 0, stream>>>(
      xb, 1024, 0, wqkvt, 1024, 0, qk, 2048, 0, bqkv, 1024, 1.0f);

  // 2b) V^T projection: vt[b][d][n] = Wv^T[d,:] . x[b][n,:] + bqkv[2048+d] (row bias)
  gemm_bt<2, false><<<dim3(16, 8, 8), 256, 0, stream>>>(
      wqkvt + (long)2048 * 1024, 1024, 0,
      xb, 1024, (long)NN * 1024,
      vt, NN, (long)DD * NN, bqkv + 2048, 1024, 1.0f);

  // 3) attention per batch-chunk
  for (int b0 = 0; b0 < 8; b0 += chunk) {
    // S = Q @ K^T / 32  (bf16 out)
    gemm_bt<0, false><<<dim3(16, 16, chunk), 256, 0, stream>>>(
        qk + (long)b0 * NN * 2048, 2048, (long)NN * 2048,
        qk + (long)b0 * NN * 2048 + 1024, 2048, (long)NN * 2048,
        S, NN, (long)NN * NN, nullptr, 1024, 0.03125f);
    // fused softmax -> mask -> softmax (in-place)
    softmax2<<<dim3(NN, chunk), 256, 0, stream>>>(S, mask, S, b0);
    // attn = w2 @ V  ( = S @ vt^T )
    gemm_bt<0, false><<<dim3(8, 16, chunk), 256, 0, stream>>>(
        S, NN, (long)NN * NN,
        vt + (long)b0 * DD * NN, NN, (long)DD * NN,
        attn + (long)b0 * NN * DD, DD, (long)NN * DD, nullptr, 2048, 1.0f);
  }

  // 4) output projection: [16384,1024] @ [1024,1024]^T + b -> fp32 out
  gemm_bt<1, true><<<dim3(8, 128, 1), 256, 0, stream>>>(
      attn, 1024, 0, woutt, 1024, 0, out, 1024, 0, bout, 1024, 1.0f);
}

// Round 4
// 635.185 us; speedup vs baseline: 1.1433x; 1.0426x over previous
//
#include <hip/hip_runtime.h>
#include <stdint.h>

// ---------------------------------------------------------------------------
// SelfAttnV3: qkv = x@Wqkv+b; S = Q@K^T/sqrt(D); p = softmax(S);
//             w2 = softmax(mask ? p : -1e20); out = (w2@V)@Wout + b_out
// Double-softmax identity: exp(-1e20-m)==0, p<=1 => w2 = mask*exp(p)/sum(mask*exp(p))
// All GEMMs bf16 MFMA (16x16x32), NT form.
// R4: XCD-locality block swizzle. 1-D grid; xcd = flat&7 (round-robin dispatch
//     assumption); each XCD owns a CONTIGUOUS range of A-stripes and all bn
//     blocks of a stripe. Effect: A-stripes fetched once per XCD, B-panel
//     (<=4MB: vt[z]/K[z]/weight panel) L2-resident. Attacks PV/S GEMM re-fetch
//     (278MB -> ~105MB predicted).
// R3 lessons: BK=64 + 8-chunk staging -> SQ_LDS_BANK_CONFLICT=0; PV GEMM was
//     HBM-bound (2.5TB/s) from cross-XCD stripe re-fetch.
// ---------------------------------------------------------------------------

#define NN 2048
#define DD 1024

typedef __attribute__((ext_vector_type(8))) __bf16 bf16x8;
typedef __attribute__((ext_vector_type(4))) float f32x4;
typedef __attribute__((ext_vector_type(8))) unsigned short us8;
typedef __attribute__((ext_vector_type(4))) unsigned short us4;

__device__ __forceinline__ unsigned short f2bf(float f) {
  unsigned u = __builtin_bit_cast(unsigned, f);
  return (unsigned short)((u + 0x7FFFu + ((u >> 16) & 1u)) >> 16);  // RNE
}
__device__ __forceinline__ float bf2f(unsigned short h) {
  unsigned u = ((unsigned)h) << 16;
  return __builtin_bit_cast(float, u);
}

// async global->LDS, 16B per lane. LDS dest: wave-uniform base + lane*16.
__device__ __forceinline__ void async16(const void* g, void* l) {
  __builtin_amdgcn_global_load_lds(
      (__attribute__((address_space(1))) void*)(uintptr_t)g,
      (__attribute__((address_space(3))) void*)(uintptr_t)l,
      16, 0, 0);
}

// ---------------------------------------------------------------------------
// fp32 -> bf16 elementwise convert (vectorized)
// ---------------------------------------------------------------------------
__global__ __launch_bounds__(256) void cvt_bf16(const float* __restrict__ src,
                                                unsigned short* __restrict__ dst,
                                                long n) {
  long i = ((long)blockIdx.x * 256 + threadIdx.x) * 4;
  long stride = (long)gridDim.x * 256 * 4;
  for (; i < n; i += stride) {
    float4 v = *reinterpret_cast<const float4*>(src + i);
    us4 o;
    o[0] = f2bf(v.x); o[1] = f2bf(v.y); o[2] = f2bf(v.z); o[3] = f2bf(v.w);
    *reinterpret_cast<us4*>(dst + i) = o;
  }
}

// ---------------------------------------------------------------------------
// fp32 [rows,cols] -> bf16 [cols,rows] transpose (for weights)
// ---------------------------------------------------------------------------
__global__ __launch_bounds__(256) void transpose_cvt(const float* __restrict__ src,
                                                     unsigned short* __restrict__ dst,
                                                     int rows, int cols) {
  __shared__ float t[32][33];
  const int tx = threadIdx.x & 31, ty = threadIdx.x >> 5;
  const int c0 = blockIdx.x * 32, r0 = blockIdx.y * 32;
#pragma unroll
  for (int i = 0; i < 32; i += 8)
    t[ty + i][tx] = src[(long)(r0 + ty + i) * cols + (c0 + tx)];
  __syncthreads();
#pragma unroll
  for (int i = 0; i < 32; i += 8)
    dst[(long)(c0 + ty + i) * rows + (r0 + tx)] = f2bf(t[tx][ty + i]);
}

// ---------------------------------------------------------------------------
// NT bf16 GEMM: C[M,N] = A[M,K] @ B[N,K]^T (*scale) (+bias)
// 128x128 tile, BK=64, 256 threads = 4 waves (2x2 of 64x64), single-buffered
// 32KB LDS, global_load_lds width-16 staging, mfma_f32_16x16x32_bf16.
// LDS row = 64 elems (128B), 16B-chunk swizzle (phys chunk p of row r holds
// logical p^(r&7)) -- conflict-free staging + reads (R3: counter hit 0).
//
// Grid: 1-D. XCD swizzle (round-robin assumption: block i -> XCD i%8):
//   xcd = flat&7; r = flat>>3; bn = r & (2^lbn-1); j = r>>lbn;
//   stripe s = xcd*(totalStripes/8) + j; bm = s & (2^lbm-1); bz = s>>lbm.
// All bn blocks of a stripe land on ONE XCD, stripes contiguous per XCD ->
// A-stripe fetched once/XCD, B-panel of that z L2-resident.
// Requires totalStripes % 8 == 0 (all call sites satisfy).
// BMODE: 0=none, 1=col bias (bias[gc]), 2=row bias (bias[gr]).
// ---------------------------------------------------------------------------
template <int BMODE, bool OUTF32>
__global__ __launch_bounds__(256) void gemm_bt(
    const unsigned short* __restrict__ A, long lda, long sA,
    const unsigned short* __restrict__ B, long ldb, long sB,
    void* __restrict__ Cv, long ldc, long sC,
    const float* __restrict__ bias, int K, float scale, int lbn, int lbm) {
  __shared__ __attribute__((aligned(16))) unsigned short As[128 * 64];
  __shared__ __attribute__((aligned(16))) unsigned short Bs[128 * 64];
  const int tid = threadIdx.x;

  // XCD-locality decode
  const int flat = blockIdx.x;
  const int xcd = flat & 7;
  const int r = flat >> 3;
  const int bn = r & ((1 << lbn) - 1);
  const int j = r >> lbn;
  const int spx = gridDim.x >> (3 + lbn);  // stripes per XCD
  const int s = xcd * spx + j;
  const long bm = s & ((1 << lbm) - 1);
  const long bz = s >> lbm;

  A += bz * sA + bm * 128 * lda;
  B += bz * sB + (long)bn * 128 * ldb;

  // staging: slot s in [0,1024): row=s>>3, phys chunk=s&7. Thread t owns slots
  // t, t+256, t+512, t+768 (rows r0+32j, same phys chunk). Logical chunk
  // fetched = (t&7)^(r0&7), invariant across j (32 == 0 mod 8).
  const int r0 = tid >> 3;
  const int kx = ((tid & 7) ^ (r0 & 7)) * 8;  // element offset in row
  const unsigned short* Ag0 = A + (long)r0 * lda + kx;
  const unsigned short* Ag1 = A + (long)(r0 + 32) * lda + kx;
  const unsigned short* Ag2 = A + (long)(r0 + 64) * lda + kx;
  const unsigned short* Ag3 = A + (long)(r0 + 96) * lda + kx;
  const unsigned short* Bg0 = B + (long)r0 * ldb + kx;
  const unsigned short* Bg1 = B + (long)(r0 + 32) * ldb + kx;
  const unsigned short* Bg2 = B + (long)(r0 + 64) * ldb + kx;
  const unsigned short* Bg3 = B + (long)(r0 + 96) * ldb + kx;
  unsigned short* lA0 = &As[tid * 8];
  unsigned short* lA1 = &As[(tid + 256) * 8];
  unsigned short* lA2 = &As[(tid + 512) * 8];
  unsigned short* lA3 = &As[(tid + 768) * 8];
  unsigned short* lB0 = &Bs[tid * 8];
  unsigned short* lB1 = &Bs[(tid + 256) * 8];
  unsigned short* lB2 = &Bs[(tid + 512) * 8];
  unsigned short* lB3 = &Bs[(tid + 768) * 8];

  f32x4 acc[4][4] = {};
  const int lane = tid & 63;
  const int wm = (tid >> 7) * 64;         // wave row (2x2 wave grid)
  const int wn = ((tid >> 6) & 1) * 64;   // wave col
  const int fr = lane & 15;               // frag row (A) / col (B)
  const int quad = lane >> 4;
  // element offsets of logical k-chunks (kk*4+quad), un-swizzled per lane:
  const int koff0 = ((quad) ^ (fr & 7)) * 8;        // kk=0
  const int koff1 = ((4 + quad) ^ (fr & 7)) * 8;    // kk=1

  for (int kt = 0; kt < K; kt += 64) {
    async16(Ag0 + kt, lA0);
    async16(Ag1 + kt, lA1);
    async16(Ag2 + kt, lA2);
    async16(Ag3 + kt, lA3);
    async16(Bg0 + kt, lB0);
    async16(Bg1 + kt, lB1);
    async16(Bg2 + kt, lB2);
    async16(Bg3 + kt, lB3);
    __syncthreads();  // compiler emits vmcnt(0) drain before barrier
#pragma unroll
    for (int kk = 0; kk < 2; kk++) {
      const int ko = kk ? koff1 : koff0;
      bf16x8 a[4], b[4];
#pragma unroll
      for (int i = 0; i < 4; i++)
        a[i] = *reinterpret_cast<const bf16x8*>(&As[(wm + i * 16 + fr) * 64 + ko]);
#pragma unroll
      for (int i = 0; i < 4; i++)
        b[i] = *reinterpret_cast<const bf16x8*>(&Bs[(wn + i * 16 + fr) * 64 + ko]);
#pragma unroll
      for (int mi = 0; mi < 4; mi++)
#pragma unroll
        for (int ni = 0; ni < 4; ni++)
          acc[mi][ni] = __builtin_amdgcn_mfma_f32_16x16x32_bf16(a[mi], b[ni], acc[mi][ni], 0, 0, 0);
    }
    __syncthreads();
  }

  // epilogue: C/D layout col=lane&15, row=(lane>>4)*4+reg (m89-verified)
  const int cr = quad * 4;
  float* Cf = (float*)Cv;
  unsigned short* Ch = (unsigned short*)Cv;
  const long crow0 = bm * 128 + wm;
  const long ccol0 = (long)bn * 128 + wn;
#pragma unroll
  for (int ni = 0; ni < 4; ni++) {
    const long gc = ccol0 + ni * 16 + fr;
    const float bc = (BMODE == 1) ? bias[gc] : 0.0f;
#pragma unroll
    for (int mi = 0; mi < 4; mi++) {
      const long gr = crow0 + mi * 16 + cr;
#pragma unroll
      for (int r2 = 0; r2 < 4; r2++) {
        const float bv = (BMODE == 2) ? bias[gr + r2] : bc;
        float v = acc[mi][ni][r2] * scale + bv;
        long idx = bz * sC + (gr + r2) * ldc + gc;
        if (OUTF32) Cf[idx] = v;
        else        Ch[idx] = f2bf(v);
      }
    }
  }
}

// ---------------------------------------------------------------------------
// Fused double softmax per row: p = softmax(s); w2 = mask*exp(p)/sum(mask*exp(p))
// One block (256 thr) per row; 8 elements/thread in registers. In-place OK.
// ---------------------------------------------------------------------------
__global__ __launch_bounds__(256) void softmax2(const unsigned short* __restrict__ S,
                                                const int* __restrict__ mask,
                                                unsigned short* __restrict__ W2,
                                                int b0) {
  const int q = blockIdx.x;
  const int zb = blockIdx.y;
  const int tid = threadIdx.x;
  const int lane = tid & 63, wave = tid >> 6;
  const long rl = ((long)zb * NN + q) * NN;
  const unsigned short* srow = S + rl;
  unsigned short* wrow = W2 + rl;
  const int* mrow = mask + ((long)(b0 + zb) * NN + q) * NN;

  us8 sv = *reinterpret_cast<const us8*>(srow + tid * 8);
  float s[8];
#pragma unroll
  for (int j = 0; j < 8; j++) s[j] = bf2f(sv[j]);

  __shared__ float redm[4], redl[4], redt[4];

  // --- softmax 1: max ---
  float m = s[0];
#pragma unroll
  for (int j = 1; j < 8; j++) m = fmaxf(m, s[j]);
  for (int o = 32; o; o >>= 1) m = fmaxf(m, __shfl_xor(m, o));
  if (lane == 0) redm[wave] = m;
  __syncthreads();
  m = fmaxf(fmaxf(redm[0], redm[1]), fmaxf(redm[2], redm[3]));

  // --- softmax 1: sum ---
  float p[8];
  float ls = 0.0f;
#pragma unroll
  for (int j = 0; j < 8; j++) { p[j] = __expf(s[j] - m); ls += p[j]; }
  for (int o = 32; o; o >>= 1) ls += __shfl_xor(ls, o);
  if (lane == 0) redl[wave] = ls;
  __syncthreads();
  ls = redl[0] + redl[1] + redl[2] + redl[3];
  const float invL = 1.0f / ls;

  // --- mask + softmax 2 (p in [0,1]: no max-sub needed; masked -> exactly 0) ---
  int4 m0 = *reinterpret_cast<const int4*>(mrow + tid * 8);
  int4 m1 = *reinterpret_cast<const int4*>(mrow + tid * 8 + 4);
  const int mk[8] = {m0.x, m0.y, m0.z, m0.w, m1.x, m1.y, m1.z, m1.w};
  float t[8];
  float ts = 0.0f;
#pragma unroll
  for (int j = 0; j < 8; j++) {
    float e = (mk[j] != 0) ? __expf(p[j] * invL) : 0.0f;
    t[j] = e;
    ts += e;
  }
  for (int o = 32; o; o >>= 1) ts += __shfl_xor(ts, o);
  if (lane == 0) redt[wave] = ts;
  __syncthreads();
  ts = redt[0] + redt[1] + redt[2] + redt[3];

  us8 ov;
  if (ts > 0.0f) {
    const float invT = 1.0f / ts;
#pragma unroll
    for (int j = 0; j < 8; j++) ov[j] = f2bf(t[j] * invT);
  } else {  // all-masked row: reference softmax of uniform -1e20 -> 1/N
#pragma unroll
    for (int j = 0; j < 8; j++) ov[j] = f2bf(1.0f / (float)NN);
  }
  *reinterpret_cast<us8*>(wrow + tid * 8) = ov;
}

// ---------------------------------------------------------------------------
extern "C" void kernel_launch(void* const* d_in, const int* in_sizes, int n_in,
                              void* d_out, int out_size, void* d_ws, size_t ws_size,
                              hipStream_t stream) {
  const float* x = (const float*)d_in[0];
  const int* mask = (const int*)d_in[1];
  const float* Wqkv = (const float*)d_in[2];
  const float* bqkv = (const float*)d_in[3];
  const float* Wout = (const float*)d_in[4];
  const float* bout = (const float*)d_in[5];
  float* out = (float*)d_out;

  char* p = (char*)d_ws;
  unsigned short* xb = (unsigned short*)p;    p += (long)16384 * 1024 * 2;   // 33.5MB
  unsigned short* wqkvt = (unsigned short*)p; p += (long)3072 * 1024 * 2;    // 6.3MB
  unsigned short* woutt = (unsigned short*)p; p += (long)1024 * 1024 * 2;    // 2.1MB
  unsigned short* qk = (unsigned short*)p;    p += (long)16384 * 2048 * 2;   // 67.1MB (Q|K per row)
  unsigned short* vt = (unsigned short*)p;    p += (long)8 * 1024 * 2048 * 2;// 33.5MB
  unsigned short* attn = (unsigned short*)p;  p += (long)16384 * 1024 * 2;   // 33.5MB
  const long fixed = (long)(p - (char*)d_ws);

  // batch chunk for S (bf16 [chunk,2048,2048]); softmax runs in-place (w2 == S)
  int chunk = 8;
  while (chunk > 1 && fixed + (long)chunk * NN * NN * 2 > (long)ws_size) chunk >>= 1;
  unsigned short* S = (unsigned short*)p;

  // 1) convert x to bf16; transpose-convert weights
  cvt_bf16<<<4096, 256, 0, stream>>>(x, xb, (long)16384 * 1024);
  transpose_cvt<<<dim3(3072 / 32, 1024 / 32), 256, 0, stream>>>(Wqkv, wqkvt, 1024, 3072);
  transpose_cvt<<<dim3(1024 / 32, 1024 / 32), 256, 0, stream>>>(Wout, woutt, 1024, 1024);

  // 2a) QK projection: [16384,1024] @ [2048,1024]^T + b -> qk bf16 [16384,2048]
  //     nbn=16 (lbn=4), nbm=128 (lbm=7), nz=1 -> 2048 blocks
  gemm_bt<1, false><<<2048, 256, 0, stream>>>(
      xb, 1024, 0, wqkvt, 1024, 0, qk, 2048, 0, bqkv, 1024, 1.0f, 4, 7);

  // 2b) V^T projection: vt[b][d][n] = Wv^T[d,:] . x[b][n,:] + bqkv[2048+d]
  //     nbn=16 (lbn=4), nbm=8 (lbm=3), nz=8 -> 1024 blocks
  gemm_bt<2, false><<<1024, 256, 0, stream>>>(
      wqkvt + (long)2048 * 1024, 1024, 0,
      xb, 1024, (long)NN * 1024,
      vt, NN, (long)DD * NN, bqkv + 2048, 1024, 1.0f, 4, 3);

  // 3) attention per batch-chunk
  for (int b0 = 0; b0 < 8; b0 += chunk) {
    // S = Q @ K^T / 32  (bf16 out): nbn=16 (lbn=4), nbm=16 (lbm=4), nz=chunk
    gemm_bt<0, false><<<16 * 16 * chunk, 256, 0, stream>>>(
        qk + (long)b0 * NN * 2048, 2048, (long)NN * 2048,
        qk + (long)b0 * NN * 2048 + 1024, 2048, (long)NN * 2048,
        S, NN, (long)NN * NN, nullptr, 1024, 0.03125f, 4, 4);
    // fused softmax -> mask -> softmax (in-place)
    softmax2<<<dim3(NN, chunk), 256, 0, stream>>>(S, mask, S, b0);
    // attn = w2 @ V: nbn=8 (lbn=3), nbm=16 (lbm=4), nz=chunk
    gemm_bt<0, false><<<8 * 16 * chunk, 256, 0, stream>>>(
        S, NN, (long)NN * NN,
        vt + (long)b0 * DD * NN, NN, (long)DD * NN,
        attn + (long)b0 * NN * DD, DD, (long)NN * DD, nullptr, 2048, 1.0f, 3, 4);
  }

  // 4) output projection: nbn=8 (lbn=3), nbm=128 (lbm=7), nz=1 -> 1024 blocks
  gemm_bt<1, true><<<1024, 256, 0, stream>>>(
      attn, 1024, 0, woutt, 1024, 0, out, 1024, 0, bout, 1024, 1.0f, 3, 7);
}

// Round 5
// 621.185 us; speedup vs baseline: 1.1691x; 1.0225x over previous
//
#include <hip/hip_runtime.h>
#include <stdint.h>

// ---------------------------------------------------------------------------
// SelfAttnV3: qkv = x@Wqkv+b; S = Q@K^T/sqrt(D); p = softmax(S);
//             w2 = softmax(mask ? p : -1e20); out = (w2@V)@Wout + b_out
// Double-softmax identity: exp(-1e20-m)==0, p<=1 => w2 = mask*exp(p)/sum(mask*exp(p))
// All GEMMs bf16 MFMA (16x16x32), NT form.
// R5: single-barrier double-buffered K-loop (BK=32, 2x(8+8)KB LDS = 32KB):
//     barrier drains the tile issued one full compute phase earlier (L2-fed ->
//     fully hidden); 1 barrier/iter instead of 2. Occupancy unchanged (32KB).
// R4 lessons: XCD swizzle works (FETCH 278->66MB, flat%8 confirmed); GEMMs are
//     latency-bound (Mfma 23%, VALU 30%, HBM 14%), drain is the stall.
// R2/R3 lesson: SQ_LDS_BANK_CONFLICT tracked staging writes, not ds_reads.
// ---------------------------------------------------------------------------

#define NN 2048
#define DD 1024

typedef __attribute__((ext_vector_type(8))) __bf16 bf16x8;
typedef __attribute__((ext_vector_type(4))) float f32x4;
typedef __attribute__((ext_vector_type(8))) unsigned short us8;
typedef __attribute__((ext_vector_type(4))) unsigned short us4;

__device__ __forceinline__ unsigned short f2bf(float f) {
  unsigned u = __builtin_bit_cast(unsigned, f);
  return (unsigned short)((u + 0x7FFFu + ((u >> 16) & 1u)) >> 16);  // RNE
}
__device__ __forceinline__ float bf2f(unsigned short h) {
  unsigned u = ((unsigned)h) << 16;
  return __builtin_bit_cast(float, u);
}

// async global->LDS, 16B per lane. LDS dest: wave-uniform base + lane*16.
__device__ __forceinline__ void async16(const void* g, void* l) {
  __builtin_amdgcn_global_load_lds(
      (__attribute__((address_space(1))) void*)(uintptr_t)g,
      (__attribute__((address_space(3))) void*)(uintptr_t)l,
      16, 0, 0);
}

// ---------------------------------------------------------------------------
// fp32 -> bf16 elementwise convert (vectorized)
// ---------------------------------------------------------------------------
__global__ __launch_bounds__(256) void cvt_bf16(const float* __restrict__ src,
                                                unsigned short* __restrict__ dst,
                                                long n) {
  long i = ((long)blockIdx.x * 256 + threadIdx.x) * 4;
  long stride = (long)gridDim.x * 256 * 4;
  for (; i < n; i += stride) {
    float4 v = *reinterpret_cast<const float4*>(src + i);
    us4 o;
    o[0] = f2bf(v.x); o[1] = f2bf(v.y); o[2] = f2bf(v.z); o[3] = f2bf(v.w);
    *reinterpret_cast<us4*>(dst + i) = o;
  }
}

// ---------------------------------------------------------------------------
// fp32 [rows,cols] -> bf16 [cols,rows] transpose (for weights)
// ---------------------------------------------------------------------------
__global__ __launch_bounds__(256) void transpose_cvt(const float* __restrict__ src,
                                                     unsigned short* __restrict__ dst,
                                                     int rows, int cols) {
  __shared__ float t[32][33];
  const int tx = threadIdx.x & 31, ty = threadIdx.x >> 5;
  const int c0 = blockIdx.x * 32, r0 = blockIdx.y * 32;
#pragma unroll
  for (int i = 0; i < 32; i += 8)
    t[ty + i][tx] = src[(long)(r0 + ty + i) * cols + (c0 + tx)];
  __syncthreads();
#pragma unroll
  for (int i = 0; i < 32; i += 8)
    dst[(long)(c0 + ty + i) * rows + (r0 + tx)] = f2bf(t[tx][ty + i]);
}

// ---------------------------------------------------------------------------
// NT bf16 GEMM: C[M,N] = A[M,K] @ B[N,K]^T (*scale) (+bias)
// 128x128 tile, BK=32, 256 threads = 4 waves (2x2 of 64x64), DOUBLE-buffered
// LDS (2 x (8KB A + 8KB B) = 32KB), global_load_lds width-16 staging,
// mfma_f32_16x16x32_bf16, 1 barrier per K-iter.
// LDS row = 32 elems (64B), 16B-chunk XOR swizzle (phys chunk p of row r holds
// logical p^(r&3)); reader offset loop-invariant per lane.
//
// Grid: 1-D, XCD-locality swizzle (R4-validated: block i -> XCD i%8):
//   xcd = flat&7; r = flat>>3; bn = r & (2^lbn-1); j = r>>lbn;
//   stripe s = xcd*(totalStripes/8) + j; bm = s & (2^lbm-1); bz = s>>lbm.
// A-stripe fetched once/XCD; B-panel of that z L2-resident.
// BMODE: 0=none, 1=col bias (bias[gc]), 2=row bias (bias[gr]).
// ---------------------------------------------------------------------------
template <int BMODE, bool OUTF32>
__global__ __launch_bounds__(256) void gemm_bt(
    const unsigned short* __restrict__ A, long lda, long sA,
    const unsigned short* __restrict__ B, long ldb, long sB,
    void* __restrict__ Cv, long ldc, long sC,
    const float* __restrict__ bias, int K, float scale, int lbn, int lbm) {
  __shared__ __attribute__((aligned(16))) unsigned short As[2][128 * 32];
  __shared__ __attribute__((aligned(16))) unsigned short Bs[2][128 * 32];
  const int tid = threadIdx.x;

  // XCD-locality decode
  const int flat = blockIdx.x;
  const int xcd = flat & 7;
  const int r = flat >> 3;
  const int bn = r & ((1 << lbn) - 1);
  const int j = r >> lbn;
  const int spx = gridDim.x >> (3 + lbn);  // stripes per XCD
  const int s = xcd * spx + j;
  const long bm = s & ((1 << lbm) - 1);
  const long bz = s >> lbm;

  A += bz * sA + bm * 128 * lda;
  B += bz * sB + (long)bn * 128 * ldb;

  // staging: slot s in [0,512): row=s>>2, phys chunk=s&3. Thread t owns slots
  // t (row r0) and t+256 (row r0+64), phys chunk t&3. Logical chunk fetched =
  // (t&3)^(r0&3) (row parity identical for r0 and r0+64).
  const int r0 = tid >> 2;
  const int kx = ((tid & 3) ^ (r0 & 3)) * 8;  // element offset in 32-elem row
  const unsigned short* Ag0 = A + (long)r0 * lda + kx;
  const unsigned short* Ag1 = A + (long)(r0 + 64) * lda + kx;
  const unsigned short* Bg0 = B + (long)r0 * ldb + kx;
  const unsigned short* Bg1 = B + (long)(r0 + 64) * ldb + kx;
  const int l0 = tid * 8, l1 = (tid + 256) * 8;

  f32x4 acc[4][4] = {};
  const int lane = tid & 63;
  const int wm = (tid >> 7) * 64;         // wave row (2x2 wave grid)
  const int wn = ((tid >> 6) & 1) * 64;   // wave col
  const int fr = lane & 15;               // frag row (A) / col (B)
  const int quad = lane >> 4;
  // physical chunk offset for logical quad, undoing staging swizzle
  // (row = wm+16i+fr ≡ fr mod 4):
  const int ko = (quad ^ (fr & 3)) * 8;

  const int nk = K >> 5;
  // preload tile 0 into buffer 0
  async16(Ag0, &As[0][l0]);
  async16(Ag1, &As[0][l1]);
  async16(Bg0, &Bs[0][l0]);
  async16(Bg1, &Bs[0][l1]);

  for (int kt = 0; kt < nk; kt++) {
    __syncthreads();  // drains tile kt (issued one compute phase ago) + frees other buf
    const int cur = kt & 1;
    if (kt + 1 < nk) {
      const long off = (long)(kt + 1) * 32;
      async16(Ag0 + off, &As[cur ^ 1][l0]);
      async16(Ag1 + off, &As[cur ^ 1][l1]);
      async16(Bg0 + off, &Bs[cur ^ 1][l0]);
      async16(Bg1 + off, &Bs[cur ^ 1][l1]);
    }
    bf16x8 a[4], b[4];
#pragma unroll
    for (int i = 0; i < 4; i++)
      a[i] = *reinterpret_cast<const bf16x8*>(&As[cur][(wm + i * 16 + fr) * 32 + ko]);
#pragma unroll
    for (int i = 0; i < 4; i++)
      b[i] = *reinterpret_cast<const bf16x8*>(&Bs[cur][(wn + i * 16 + fr) * 32 + ko]);
#pragma unroll
    for (int mi = 0; mi < 4; mi++)
#pragma unroll
      for (int ni = 0; ni < 4; ni++)
        acc[mi][ni] = __builtin_amdgcn_mfma_f32_16x16x32_bf16(a[mi], b[ni], acc[mi][ni], 0, 0, 0);
  }

  // epilogue: C/D layout col=lane&15, row=(lane>>4)*4+reg (m89-verified)
  const int cr = quad * 4;
  float* Cf = (float*)Cv;
  unsigned short* Ch = (unsigned short*)Cv;
  const long crow0 = bm * 128 + wm;
  const long ccol0 = (long)bn * 128 + wn;
#pragma unroll
  for (int ni = 0; ni < 4; ni++) {
    const long gc = ccol0 + ni * 16 + fr;
    const float bc = (BMODE == 1) ? bias[gc] : 0.0f;
#pragma unroll
    for (int mi = 0; mi < 4; mi++) {
      const long gr = crow0 + mi * 16 + cr;
#pragma unroll
      for (int r2 = 0; r2 < 4; r2++) {
        const float bv = (BMODE == 2) ? bias[gr + r2] : bc;
        float v = acc[mi][ni][r2] * scale + bv;
        long idx = bz * sC + (gr + r2) * ldc + gc;
        if (OUTF32) Cf[idx] = v;
        else        Ch[idx] = f2bf(v);
      }
    }
  }
}

// ---------------------------------------------------------------------------
// Fused double softmax per row: p = softmax(s); w2 = mask*exp(p)/sum(mask*exp(p))
// One block (256 thr) per row; 8 elements/thread in registers. In-place OK.
// ---------------------------------------------------------------------------
__global__ __launch_bounds__(256) void softmax2(const unsigned short* __restrict__ S,
                                                const int* __restrict__ mask,
                                                unsigned short* __restrict__ W2,
                                                int b0) {
  const int q = blockIdx.x;
  const int zb = blockIdx.y;
  const int tid = threadIdx.x;
  const int lane = tid & 63, wave = tid >> 6;
  const long rl = ((long)zb * NN + q) * NN;
  const unsigned short* srow = S + rl;
  unsigned short* wrow = W2 + rl;
  const int* mrow = mask + ((long)(b0 + zb) * NN + q) * NN;

  us8 sv = *reinterpret_cast<const us8*>(srow + tid * 8);
  float s[8];
#pragma unroll
  for (int j = 0; j < 8; j++) s[j] = bf2f(sv[j]);

  __shared__ float redm[4], redl[4], redt[4];

  // --- softmax 1: max ---
  float m = s[0];
#pragma unroll
  for (int j = 1; j < 8; j++) m = fmaxf(m, s[j]);
  for (int o = 32; o; o >>= 1) m = fmaxf(m, __shfl_xor(m, o));
  if (lane == 0) redm[wave] = m;
  __syncthreads();
  m = fmaxf(fmaxf(redm[0], redm[1]), fmaxf(redm[2], redm[3]));

  // --- softmax 1: sum ---
  float p[8];
  float ls = 0.0f;
#pragma unroll
  for (int j = 0; j < 8; j++) { p[j] = __expf(s[j] - m); ls += p[j]; }
  for (int o = 32; o; o >>= 1) ls += __shfl_xor(ls, o);
  if (lane == 0) redl[wave] = ls;
  __syncthreads();
  ls = redl[0] + redl[1] + redl[2] + redl[3];
  const float invL = 1.0f / ls;

  // --- mask + softmax 2 (p in [0,1]: no max-sub needed; masked -> exactly 0) ---
  int4 m0 = *reinterpret_cast<const int4*>(mrow + tid * 8);
  int4 m1 = *reinterpret_cast<const int4*>(mrow + tid * 8 + 4);
  const int mk[8] = {m0.x, m0.y, m0.z, m0.w, m1.x, m1.y, m1.z, m1.w};
  float t[8];
  float ts = 0.0f;
#pragma unroll
  for (int j = 0; j < 8; j++) {
    float e = (mk[j] != 0) ? __expf(p[j] * invL) : 0.0f;
    t[j] = e;
    ts += e;
  }
  for (int o = 32; o; o >>= 1) ts += __shfl_xor(ts, o);
  if (lane == 0) redt[wave] = ts;
  __syncthreads();
  ts = redt[0] + redt[1] + redt[2] + redt[3];

  us8 ov;
  if (ts > 0.0f) {
    const float invT = 1.0f / ts;
#pragma unroll
    for (int j = 0; j < 8; j++) ov[j] = f2bf(t[j] * invT);
  } else {  // all-masked row: reference softmax of uniform -1e20 -> 1/N
#pragma unroll
    for (int j = 0; j < 8; j++) ov[j] = f2bf(1.0f / (float)NN);
  }
  *reinterpret_cast<us8*>(wrow + tid * 8) = ov;
}

// ---------------------------------------------------------------------------
extern "C" void kernel_launch(void* const* d_in, const int* in_sizes, int n_in,
                              void* d_out, int out_size, void* d_ws, size_t ws_size,
                              hipStream_t stream) {
  const float* x = (const float*)d_in[0];
  const int* mask = (const int*)d_in[1];
  const float* Wqkv = (const float*)d_in[2];
  const float* bqkv = (const float*)d_in[3];
  const float* Wout = (const float*)d_in[4];
  const float* bout = (const float*)d_in[5];
  float* out = (float*)d_out;

  char* p = (char*)d_ws;
  unsigned short* xb = (unsigned short*)p;    p += (long)16384 * 1024 * 2;   // 33.5MB
  unsigned short* wqkvt = (unsigned short*)p; p += (long)3072 * 1024 * 2;    // 6.3MB
  unsigned short* woutt = (unsigned short*)p; p += (long)1024 * 1024 * 2;    // 2.1MB
  unsigned short* qk = (unsigned short*)p;    p += (long)16384 * 2048 * 2;   // 67.1MB (Q|K per row)
  unsigned short* vt = (unsigned short*)p;    p += (long)8 * 1024 * 2048 * 2;// 33.5MB
  unsigned short* attn = (unsigned short*)p;  p += (long)16384 * 1024 * 2;   // 33.5MB
  const long fixed = (long)(p - (char*)d_ws);

  // batch chunk for S (bf16 [chunk,2048,2048]); softmax runs in-place (w2 == S)
  int chunk = 8;
  while (chunk > 1 && fixed + (long)chunk * NN * NN * 2 > (long)ws_size) chunk >>= 1;
  unsigned short* S = (unsigned short*)p;

  // 1) convert x to bf16; transpose-convert weights
  cvt_bf16<<<4096, 256, 0, stream>>>(x, xb, (long)16384 * 1024);
  transpose_cvt<<<dim3(3072 / 32, 1024 / 32), 256, 0, stream>>>(Wqkv, wqkvt, 1024, 3072);
  transpose_cvt<<<dim3(1024 / 32, 1024 / 32), 256, 0, stream>>>(Wout, woutt, 1024, 1024);

  // 2a) QK projection: [16384,1024] @ [2048,1024]^T + b -> qk bf16 [16384,2048]
  //     nbn=16 (lbn=4), nbm=128 (lbm=7), nz=1 -> 2048 blocks
  gemm_bt<1, false><<<2048, 256, 0, stream>>>(
      xb, 1024, 0, wqkvt, 1024, 0, qk, 2048, 0, bqkv, 1024, 1.0f, 4, 7);

  // 2b) V^T projection: vt[b][d][n] = Wv^T[d,:] . x[b][n,:] + bqkv[2048+d]
  //     nbn=16 (lbn=4), nbm=8 (lbm=3), nz=8 -> 1024 blocks
  gemm_bt<2, false><<<1024, 256, 0, stream>>>(
      wqkvt + (long)2048 * 1024, 1024, 0,
      xb, 1024, (long)NN * 1024,
      vt, NN, (long)DD * NN, bqkv + 2048, 1024, 1.0f, 4, 3);

  // 3) attention per batch-chunk
  for (int b0 = 0; b0 < 8; b0 += chunk) {
    // S = Q @ K^T / 32  (bf16 out): nbn=16 (lbn=4), nbm=16 (lbm=4), nz=chunk
    gemm_bt<0, false><<<16 * 16 * chunk, 256, 0, stream>>>(
        qk + (long)b0 * NN * 2048, 2048, (long)NN * 2048,
        qk + (long)b0 * NN * 2048 + 1024, 2048, (long)NN * 2048,
        S, NN, (long)NN * NN, nullptr, 1024, 0.03125f, 4, 4);
    // fused softmax -> mask -> softmax (in-place)
    softmax2<<<dim3(NN, chunk), 256, 0, stream>>>(S, mask, S, b0);
    // attn = w2 @ V: nbn=8 (lbn=3), nbm=16 (lbm=4), nz=chunk
    gemm_bt<0, false><<<8 * 16 * chunk, 256, 0, stream>>>(
        S, NN, (long)NN * NN,
        vt + (long)b0 * DD * NN, NN, (long)DD * NN,
        attn + (long)b0 * NN * DD, DD, (long)NN * DD, nullptr, 2048, 1.0f, 3, 4);
  }

  // 4) output projection: nbn=8 (lbn=3), nbm=128 (lbm=7), nz=1 -> 1024 blocks
  gemm_bt<1, true><<<1024, 256, 0, stream>>>(
      attn, 1024, 0, woutt, 1024, 0, out, 1024, 0, bout, 1024, 1.0f, 3, 7);
}